// Round 1
// baseline (1819.531 us; speedup 1.0000x reference)
//
#include <hip/hip_runtime.h>

#define R   256
#define S   128
#define CM  256
#define CH  32
#define CZ  128

// ---------------------------------------------------------------------------
// K0: scale[i*R+j] = 1 / (1e-3 + sum_s mask[s,i]*mask[s,j])
// ---------------------------------------------------------------------------
__global__ __launch_bounds__(256) void k_norm(const float* __restrict__ mask,
                                              float* __restrict__ scale) {
    int i = blockIdx.x, j = threadIdx.x;
    float acc = 0.f;
    for (int s = 0; s < S; ++s) acc += mask[s * R + i] * mask[s * R + j];
    scale[i * R + j] = 1.0f / (1e-3f + acc);
}

// ---------------------------------------------------------------------------
// K1: LayerNorm over c_m + both projections, one block per (s,r) row.
// Writes A[r][s][c] and B[r][s][c]  (seq-transposed layout for the outer GEMM).
// ---------------------------------------------------------------------------
__global__ __launch_bounds__(256) void k_lnproj(
    const float* __restrict__ m, const float* __restrict__ mask,
    const float* __restrict__ g, const float* __restrict__ beta,
    const float* __restrict__ w1, const float* __restrict__ b1,
    const float* __restrict__ w2, const float* __restrict__ b2,
    float* __restrict__ A, float* __restrict__ B) {
    int p = blockIdx.x;            // p = s*R + r
    int s = p >> 8, r = p & 255;
    int t = threadIdx.x;
    __shared__ float mn[CM];
    __shared__ float red[8];
    __shared__ float part[4][64];

    float x = m[(size_t)p * CM + t];
    float sum = x, sq = x * x;
    #pragma unroll
    for (int off = 32; off; off >>= 1) {
        sum += __shfl_down(sum, off);
        sq  += __shfl_down(sq,  off);
    }
    int wave = t >> 6, lane = t & 63;
    if (lane == 0) { red[wave * 2] = sum; red[wave * 2 + 1] = sq; }
    __syncthreads();
    float tot = red[0] + red[2] + red[4] + red[6];
    float tsq = red[1] + red[3] + red[5] + red[7];
    float mean = tot * (1.0f / CM);
    float var  = tsq * (1.0f / CM) - mean * mean;
    float inv  = rsqrtf(var + 1e-5f);
    mn[t] = (x - mean) * inv * g[t] + beta[t];
    __syncthreads();

    // 64 outputs (32 a + 32 b); 4 partial-K groups of 64 threads each
    int o = t & 63, q = t >> 6;
    int col = o & 31;
    const float* w = (o < CH) ? w1 : w2;
    float acc = 0.f;
    int k0 = q * 64;
    #pragma unroll 8
    for (int k = k0; k < k0 + 64; ++k) acc += mn[k] * w[k * CH + col];
    part[q][o] = acc;
    __syncthreads();
    if (t < 64) {
        float v = part[0][o] + part[1][o] + part[2][o] + part[3][o];
        float bias = (o < CH) ? b1[col] : b2[col];
        v = (v + bias) * mask[p];
        float* dst = (o < CH) ? A : B;
        dst[((size_t)r * S + s) * CH + col] = v;
    }
}

// ---------------------------------------------------------------------------
// K2: outer[i,j,c,e] = sum_s A[i,s,c]*B[j,s,e] for i in [ib, ib+2*gridDim.y)
// One block = 2x2 (i,j) pairs; each wave owns one pair; 16 accums/thread.
// Writes chunk-local OC[((i-ib)*R + j)*1024 + c*32 + e].
// ---------------------------------------------------------------------------
__global__ __launch_bounds__(256) void k_outer(
    const float* __restrict__ A, const float* __restrict__ B,
    float* __restrict__ OC, int ib) {
    __shared__ float shA[2][S * CH];
    __shared__ float shB[2][S * CH];
    int t = threadIdx.x;
    int i0 = ib + blockIdx.y * 2;
    int j0 = blockIdx.x * 2;
    #pragma unroll
    for (int u = t * 4; u < S * CH; u += 1024) {
        *(float4*)&shA[0][u] = *(const float4*)&A[(size_t)(i0    ) * S * CH + u];
        *(float4*)&shA[1][u] = *(const float4*)&A[(size_t)(i0 + 1) * S * CH + u];
        *(float4*)&shB[0][u] = *(const float4*)&B[(size_t)(j0    ) * S * CH + u];
        *(float4*)&shB[1][u] = *(const float4*)&B[(size_t)(j0 + 1) * S * CH + u];
    }
    __syncthreads();
    int sub = t >> 6;                 // wave id: which (ii,jj) pair
    int ii = sub >> 1, jj = sub & 1;
    int idx = t & 63;
    int c4 = (idx >> 3) * 4;
    int e4 = (idx & 7) * 4;
    float acc[4][4];
    #pragma unroll
    for (int a = 0; a < 4; a++)
        #pragma unroll
        for (int b = 0; b < 4; b++) acc[a][b] = 0.f;
    const float* pa = shA[ii];
    const float* pb = shB[jj];
    #pragma unroll 4
    for (int s = 0; s < S; ++s) {
        float4 av = *(const float4*)&pa[s * CH + c4];
        float4 bv = *(const float4*)&pb[s * CH + e4];
        float aa[4] = {av.x, av.y, av.z, av.w};
        float bb[4] = {bv.x, bv.y, bv.z, bv.w};
        #pragma unroll
        for (int a = 0; a < 4; a++)
            #pragma unroll
            for (int b = 0; b < 4; b++) acc[a][b] += aa[a] * bb[b];
    }
    size_t base = ((size_t)(blockIdx.y * 2 + ii) * R + (j0 + jj)) * (CH * CH);
    #pragma unroll
    for (int a = 0; a < 4; a++) {
        float4 v = make_float4(acc[a][0], acc[a][1], acc[a][2], acc[a][3]);
        *(float4*)&OC[base + (size_t)(c4 + a) * CH + e4] = v;
    }
}

// ---------------------------------------------------------------------------
// K3: out[row, z] = (sum_f OC[row, f]*w_out[f, z] + b_out[z]) * scale[row]
// Block = 64 rows x 128 z, K-tile 32, w_out staged in LDS (amortized 64x).
// ---------------------------------------------------------------------------
#define KT 32
__global__ __launch_bounds__(256) void k_proj(
    const float* __restrict__ OC, const float* __restrict__ w_out,
    const float* __restrict__ b_out, const float* __restrict__ scale,
    float* __restrict__ out, int ib) {
    __shared__ float shR[KT][68];    // [k][row], stride 68: 16B-aligned, low conflict
    __shared__ float shW[KT][CZ];
    int t = threadIdx.x;
    int r0 = blockIdx.x * 64;        // chunk-local row
    int tx = t & 31, ty = t >> 5;    // z4 = tx*4, rows ty*8..ty*8+7
    float acc[8][4];
    #pragma unroll
    for (int a = 0; a < 8; a++)
        #pragma unroll
        for (int b = 0; b < 4; b++) acc[a][b] = 0.f;

    for (int kt = 0; kt < CH * CH; kt += KT) {
        // stage 64 rows x 32 k (transposed into [k][row])
        #pragma unroll
        for (int p = 0; p < 8; ++p) {
            int v = t + 256 * p;
            int row = v >> 5, k = v & 31;
            shR[k][row] = OC[(size_t)(r0 + row) * (CH * CH) + kt + k];
        }
        // stage 32 k x 128 z of w_out
        #pragma unroll
        for (int p = 0; p < 4; ++p) {
            int v4 = t * 4 + p * 1024;
            int k = v4 >> 7, z = v4 & 127;
            *(float4*)&shW[k][z] = *(const float4*)&w_out[(size_t)(kt + k) * CZ + z];
        }
        __syncthreads();
        #pragma unroll 8
        for (int k = 0; k < KT; ++k) {
            float4 wv = *(const float4*)&shW[k][tx * 4];
            float4 a0 = *(const float4*)&shR[k][ty * 8];
            float4 a1 = *(const float4*)&shR[k][ty * 8 + 4];
            float ar[8] = {a0.x, a0.y, a0.z, a0.w, a1.x, a1.y, a1.z, a1.w};
            float wr[4] = {wv.x, wv.y, wv.z, wv.w};
            #pragma unroll
            for (int a = 0; a < 8; a++)
                #pragma unroll
                for (int b = 0; b < 4; b++) acc[a][b] += ar[a] * wr[b];
        }
        __syncthreads();
    }
    float4 bz = *(const float4*)&b_out[tx * 4];
    float bb[4] = {bz.x, bz.y, bz.z, bz.w};
    #pragma unroll
    for (int a = 0; a < 8; a++) {
        int grow = ib * R + r0 + ty * 8 + a;   // global pair index i*R+j
        float sc = scale[grow];
        float4 v;
        v.x = (acc[a][0] + bb[0]) * sc;
        v.y = (acc[a][1] + bb[1]) * sc;
        v.z = (acc[a][2] + bb[2]) * sc;
        v.w = (acc[a][3] + bb[3]) * sc;
        *(float4*)&out[(size_t)grow * CZ + tx * 4] = v;
    }
}

// ---------------------------------------------------------------------------
extern "C" void kernel_launch(void* const* d_in, const int* in_sizes, int n_in,
                              void* d_out, int out_size, void* d_ws, size_t ws_size,
                              hipStream_t stream) {
    const float* m    = (const float*)d_in[0];
    const float* mask = (const float*)d_in[1];
    const float* g    = (const float*)d_in[2];
    const float* be   = (const float*)d_in[3];
    const float* w1   = (const float*)d_in[4];
    const float* b1   = (const float*)d_in[5];
    const float* w2   = (const float*)d_in[6];
    const float* b2   = (const float*)d_in[7];
    const float* wo   = (const float*)d_in[8];
    const float* bo   = (const float*)d_in[9];
    float* out = (float*)d_out;

    char* ws = (char*)d_ws;
    float* A     = (float*)ws;                  // R*S*CH = 4 MB
    float* B     = A + (size_t)R * S * CH;      // 4 MB
    float* scale = B + (size_t)R * S * CH;      // R*R = 256 KB
    float* OC    = scale + (size_t)R * R;       // chunk buffer: CI MB

    size_t fixed = ((size_t)R * S * CH * 2 + (size_t)R * R) * sizeof(float);
    int CI = 32;                                // i-rows per chunk (chunk = CI MB)
    while (CI > 2 && fixed + (size_t)CI * R * CH * CH * sizeof(float) > ws_size)
        CI >>= 1;

    k_norm<<<R, R, 0, stream>>>(mask, scale);
    k_lnproj<<<S * R, 256, 0, stream>>>(m, mask, g, be, w1, b1, w2, b2, A, B);
    for (int ib = 0; ib < R; ib += CI) {
        dim3 go(R / 2, CI / 2);
        k_outer<<<go, 256, 0, stream>>>(A, B, OC, ib);
        k_proj<<<CI * 4, 256, 0, stream>>>(OC, wo, bo, scale, out, ib);
    }
}

// Round 2
// 286.819 us; speedup vs baseline: 6.3438x; 6.3438x over previous
//
#include <hip/hip_runtime.h>

#define R   256
#define S   128
#define CM  256
#define CH  32
#define CZ  128

typedef __attribute__((ext_vector_type(8))) short short8;
typedef __attribute__((ext_vector_type(4))) float f32x4;
typedef unsigned short ushort_t;

__device__ inline ushort_t f2bf(float f) {
    union { float f; unsigned u; } v; v.f = f;
    unsigned u = v.u;
    unsigned r = u + 0x7FFF + ((u >> 16) & 1);
    return (ushort_t)(r >> 16);
}

// ---------------------------------------------------------------------------
// K0: scale[i*R+j] = 1 / (1e-3 + sum_s mask[s,i]*mask[s,j])
// ---------------------------------------------------------------------------
__global__ __launch_bounds__(256) void k_norm(const float* __restrict__ mask,
                                              float* __restrict__ scale) {
    int i = blockIdx.x, j = threadIdx.x;
    float acc = 0.f;
    for (int s = 0; s < S; ++s) acc += mask[s * R + i] * mask[s * R + j];
    scale[i * R + j] = 1.0f / (1e-3f + acc);
}

// ---------------------------------------------------------------------------
// K0b: WT[z][k] = bf16(w_out[k][z])   (1024 x 128 -> 128 x 1024)
// ---------------------------------------------------------------------------
__global__ __launch_bounds__(256) void k_wt(const float* __restrict__ w_out,
                                            ushort_t* __restrict__ WT) {
    int z = blockIdx.x, t = threadIdx.x;
    #pragma unroll
    for (int q = 0; q < 4; ++q) {
        int k = q * 256 + t;
        WT[(size_t)z * 1024 + k] = f2bf(w_out[(size_t)k * CZ + z]);
    }
}

// ---------------------------------------------------------------------------
// K1: LayerNorm + both projections, one block per (s,r) row.
// Writes Abig[(r*32+c)][s], BbigT[(r*32+e)][s]  (bf16, GEMM-ready layout).
// ---------------------------------------------------------------------------
__global__ __launch_bounds__(256) void k_lnproj(
    const float* __restrict__ m, const float* __restrict__ mask,
    const float* __restrict__ g, const float* __restrict__ beta,
    const float* __restrict__ w1, const float* __restrict__ b1,
    const float* __restrict__ w2, const float* __restrict__ b2,
    ushort_t* __restrict__ Abig, ushort_t* __restrict__ BbigT) {
    int p = blockIdx.x;            // p = s*R + r
    int s = p >> 8, r = p & 255;
    int t = threadIdx.x;
    __shared__ float mn[CM];
    __shared__ float red[8];
    __shared__ float part[4][64];

    float x = m[(size_t)p * CM + t];
    float sum = x, sq = x * x;
    #pragma unroll
    for (int off = 32; off; off >>= 1) {
        sum += __shfl_down(sum, off);
        sq  += __shfl_down(sq,  off);
    }
    int wave = t >> 6, lane = t & 63;
    if (lane == 0) { red[wave * 2] = sum; red[wave * 2 + 1] = sq; }
    __syncthreads();
    float tot = red[0] + red[2] + red[4] + red[6];
    float tsq = red[1] + red[3] + red[5] + red[7];
    float mean = tot * (1.0f / CM);
    float var  = tsq * (1.0f / CM) - mean * mean;
    float inv  = rsqrtf(var + 1e-5f);
    mn[t] = (x - mean) * inv * g[t] + beta[t];
    __syncthreads();

    int o = t & 63, q = t >> 6;
    int col = o & 31;
    const float* w = (o < CH) ? w1 : w2;
    float acc = 0.f;
    int k0 = q * 64;
    #pragma unroll 8
    for (int k = k0; k < k0 + 64; ++k) acc += mn[k] * w[k * CH + col];
    part[q][o] = acc;
    __syncthreads();
    if (t < 64) {
        float v = part[0][o] + part[1][o] + part[2][o] + part[3][o];
        float bias = (o < CH) ? b1[col] : b2[col];
        v = (v + bias) * mask[p];
        ushort_t* dst = (o < CH) ? Abig : BbigT;
        dst[((size_t)r * CH + col) * S + s] = f2bf(v);
    }
}

// ---------------------------------------------------------------------------
// K2: bf16 MFMA GEMM  D[m][n] = sum_k Abig[m][k] * BbigT[n][k]
//     m = i*32+c (chunk-local), n = j*32+e, k = s.
//     128x128 tile/block, XOR-swizzled LDS (no padding, 64 KB total).
//     Writes OC[(i_l*256+j)*1024 + c*32+e] as bf16.
// ---------------------------------------------------------------------------
__global__ __launch_bounds__(256) void k_outer(
    const ushort_t* __restrict__ Abig, const ushort_t* __restrict__ BbigT,
    ushort_t* __restrict__ OC, int ib) {
    __shared__ ushort_t shA[128 * 128];
    __shared__ ushort_t shB[128 * 128];
    int t = threadIdx.x;
    int mb = ib * CH + blockIdx.y * 128;    // global row in (i*32+c) space
    int nb = blockIdx.x * 128;              // global col in (j*32+e) space

    // stage both tiles (K=128 = full rows -> contiguous 32KB each)
    #pragma unroll
    for (int it = 0; it < 8; ++it) {
        int v = t + it * 256;
        int row = v >> 4, chk = v & 15;
        int sw = (chk ^ (row & 7)) << 3;    // 16B-chunk XOR swizzle
        *(float4*)&shA[row * 128 + sw] =
            *(const float4*)&Abig[(size_t)(mb + row) * S + (chk << 3)];
        *(float4*)&shB[row * 128 + sw] =
            *(const float4*)&BbigT[(size_t)(nb + row) * S + (chk << 3)];
    }
    __syncthreads();

    int w = t >> 6, lane = t & 63;
    int quad = lane >> 4, l15 = lane & 15;
    int wm = (w & 1) * 64, wn = (w >> 1) * 64;

    f32x4 acc[4][4];
    #pragma unroll
    for (int a = 0; a < 4; a++)
        #pragma unroll
        for (int b = 0; b < 4; b++) acc[a][b] = (f32x4)(0.f);

    #pragma unroll
    for (int ks = 0; ks < 4; ++ks) {        // K = 4 * 32
        int qk = ks * 4 + quad;             // 16B chunk index within row
        short8 af[4], bf[4];
        #pragma unroll
        for (int mt = 0; mt < 4; ++mt) {
            int mm = wm + mt * 16 + l15;
            af[mt] = *(const short8*)&shA[mm * 128 + ((qk ^ (mm & 7)) << 3)];
        }
        #pragma unroll
        for (int nt = 0; nt < 4; ++nt) {
            int nn = wn + nt * 16 + l15;
            bf[nt] = *(const short8*)&shB[nn * 128 + ((qk ^ (nn & 7)) << 3)];
        }
        #pragma unroll
        for (int mt = 0; mt < 4; ++mt)
            #pragma unroll
            for (int nt = 0; nt < 4; ++nt)
                acc[mt][nt] = __builtin_amdgcn_mfma_f32_16x16x32_bf16(
                    af[mt], bf[nt], acc[mt][nt], 0, 0, 0);
    }

    // epilogue: D row = quad*4+reg (m-space), col = l15 (n-space)
    #pragma unroll
    for (int mt = 0; mt < 4; ++mt) {
        #pragma unroll
        for (int reg = 0; reg < 4; ++reg) {
            int lm = blockIdx.y * 128 + wm + mt * 16 + quad * 4 + reg; // chunk-local m
            int il = lm >> 5, c = lm & 31;
            #pragma unroll
            for (int nt = 0; nt < 4; ++nt) {
                int gn = nb + wn + nt * 16 + l15;
                int j = gn >> 5, e = gn & 31;
                OC[(((size_t)il * R + j) << 10) + c * 32 + e] =
                    f2bf(acc[mt][nt][reg]);
            }
        }
    }
}

// ---------------------------------------------------------------------------
// K3: out[p][z] = (sum_k OC[p][k] * WT[z][k] + b_out[z]) * scale[p]
//     M = CI*256 (pairs), N = 128, K = 1024.  No LDS: A-frags coalesce to
//     full 64B lines from OC; WT (256 KB) streams from L2.
//     Wave handles 32 rows (2 m-tiles) x all 128 z.
// ---------------------------------------------------------------------------
__global__ __launch_bounds__(256) void k_proj(
    const ushort_t* __restrict__ OC, const ushort_t* __restrict__ WT,
    const float* __restrict__ b_out, const float* __restrict__ scale,
    float* __restrict__ out, int ib) {
    int t = threadIdx.x;
    int w = t >> 6, lane = t & 63;
    int quad = lane >> 4, l15 = lane & 15;
    int rb = blockIdx.x * 128 + w * 32;     // chunk-local pair row base

    f32x4 acc[2][8];
    #pragma unroll
    for (int a = 0; a < 2; a++)
        #pragma unroll
        for (int b = 0; b < 8; b++) acc[a][b] = (f32x4)(0.f);

    #pragma unroll 2
    for (int kk = 0; kk < 32; ++kk) {       // K = 32 * 32
        int ko = kk * 32 + quad * 8;        // ushort offset within row
        short8 af[2], bf[8];
        #pragma unroll
        for (int mt = 0; mt < 2; ++mt)
            af[mt] = *(const short8*)&OC[(size_t)(rb + mt * 16 + l15) * 1024 + ko];
        #pragma unroll
        for (int nt = 0; nt < 8; ++nt)
            bf[nt] = *(const short8*)&WT[(size_t)(nt * 16 + l15) * 1024 + ko];
        #pragma unroll
        for (int mt = 0; mt < 2; ++mt)
            #pragma unroll
            for (int nt = 0; nt < 8; ++nt)
                acc[mt][nt] = __builtin_amdgcn_mfma_f32_16x16x32_bf16(
                    af[mt], bf[nt], acc[mt][nt], 0, 0, 0);
    }

    float bz[8];
    #pragma unroll
    for (int nt = 0; nt < 8; ++nt) bz[nt] = b_out[nt * 16 + l15];

    #pragma unroll
    for (int mt = 0; mt < 2; ++mt) {
        #pragma unroll
        for (int reg = 0; reg < 4; ++reg) {
            int p = rb + mt * 16 + quad * 4 + reg;      // chunk-local pair
            int pg = ib * R + p;                        // global pair
            float sc = scale[pg];
            #pragma unroll
            for (int nt = 0; nt < 8; ++nt) {
                int z = nt * 16 + l15;
                out[(size_t)pg * CZ + z] = (acc[mt][nt][reg] + bz[nt]) * sc;
            }
        }
    }
}

// ---------------------------------------------------------------------------
extern "C" void kernel_launch(void* const* d_in, const int* in_sizes, int n_in,
                              void* d_out, int out_size, void* d_ws, size_t ws_size,
                              hipStream_t stream) {
    const float* m    = (const float*)d_in[0];
    const float* mask = (const float*)d_in[1];
    const float* g    = (const float*)d_in[2];
    const float* be   = (const float*)d_in[3];
    const float* w1   = (const float*)d_in[4];
    const float* b1   = (const float*)d_in[5];
    const float* w2   = (const float*)d_in[6];
    const float* b2   = (const float*)d_in[7];
    const float* wo   = (const float*)d_in[8];
    const float* bo   = (const float*)d_in[9];
    float* out = (float*)d_out;

    char* ws = (char*)d_ws;
    ushort_t* Abig  = (ushort_t*)ws;                        // 8192*128*2 = 2 MB
    ushort_t* BbigT = Abig + (size_t)R * CH * S;            // 2 MB
    ushort_t* WT    = BbigT + (size_t)R * CH * S;           // 128*1024*2 = 256 KB
    float*    scale = (float*)(WT + (size_t)CZ * CH * CH);  // 256 KB
    ushort_t* OC    = (ushort_t*)(scale + (size_t)R * R);   // CI*256*1024*2 B

    size_t fixed = (size_t)R * CH * S * 2 * 2 + (size_t)CZ * CH * CH * 2
                 + (size_t)R * R * 4;
    int CI = 256;                                           // i's per chunk
    while (CI > 4 && fixed + (size_t)CI * R * CH * CH * 2 > ws_size)
        CI >>= 1;

    k_norm<<<R, R, 0, stream>>>(mask, scale);
    k_wt<<<CZ, 256, 0, stream>>>(wo, WT);
    k_lnproj<<<S * R, 256, 0, stream>>>(m, mask, g, be, w1, b1, w2, b2, Abig, BbigT);
    for (int ib = 0; ib < R; ib += CI) {
        dim3 go(64, CI / 4);
        k_outer<<<go, 256, 0, stream>>>(Abig, BbigT, OC, ib);
        k_proj<<<CI * 2, 256, 0, stream>>>(OC, WT, bo, scale, out, ib);
    }
}

// Round 3
// 210.650 us; speedup vs baseline: 8.6377x; 1.3616x over previous
//
#include <hip/hip_runtime.h>

#define R   256
#define S   128
#define CM  256
#define CH  32
#define CZ  128

typedef __attribute__((ext_vector_type(8))) short short8;
typedef __attribute__((ext_vector_type(4))) float f32x4;
typedef unsigned short ushort_t;

__device__ inline ushort_t f2bf(float f) {
    union { float f; unsigned u; } v; v.f = f;
    unsigned u = v.u;
    unsigned r = u + 0x7FFF + ((u >> 16) & 1);
    return (ushort_t)(r >> 16);
}

// ---------------------------------------------------------------------------
// K0: scale[i*R+j] = 1 / (1e-3 + sum_s mask[s,i]*mask[s,j])
// ---------------------------------------------------------------------------
__global__ __launch_bounds__(256) void k_norm(const float* __restrict__ mask,
                                              float* __restrict__ scale) {
    int i = blockIdx.x, j = threadIdx.x;
    float acc = 0.f;
    for (int s = 0; s < S; ++s) acc += mask[s * R + i] * mask[s * R + j];
    scale[i * R + j] = 1.0f / (1e-3f + acc);
}

// ---------------------------------------------------------------------------
// K0b: WT[z][k] = bf16(w_out[k][z])   (1024 x 128 -> 128 x 1024)
// ---------------------------------------------------------------------------
__global__ __launch_bounds__(256) void k_wt(const float* __restrict__ w_out,
                                            ushort_t* __restrict__ WT) {
    int z = blockIdx.x, t = threadIdx.x;
    #pragma unroll
    for (int q = 0; q < 4; ++q) {
        int k = q * 256 + t;
        WT[(size_t)z * 1024 + k] = f2bf(w_out[(size_t)k * CZ + z]);
    }
}

// ---------------------------------------------------------------------------
// K0c: WcatT[ch][k] = bf16( ch<32 ? w1[k][ch] : w2[k][ch-32] )   [64][256]
// ---------------------------------------------------------------------------
__global__ __launch_bounds__(256) void k_wprep(const float* __restrict__ w1,
                                               const float* __restrict__ w2,
                                               ushort_t* __restrict__ WcatT) {
    int ch = blockIdx.x, k = threadIdx.x;
    const float* w = (ch < CH) ? w1 : w2;
    WcatT[(size_t)ch * CM + k] = f2bf(w[(size_t)k * CH + (ch & 31)]);
}

// ---------------------------------------------------------------------------
// K1: LN + both projections via MFMA.
// Block = 4 r x 16 s = 64 rows (m = r_l*16 + s_l), K=256, N=64 (a|b chans).
// grid 512: blockIdx = rg*8 + sg;  s0 = sg*16, r0 = rg*4.
// LDS: mn tile 32 KB + W tile 32 KB, 16B-chunk XOR swizzle (phys = ck ^ (row&15)).
// Epilogue: lane holds 4 consecutive s per (r,c) -> aligned 8B stores;
// a block completes whole 32B sectors of Abig/BbigT (no partial-line writes).
// ---------------------------------------------------------------------------
__global__ __launch_bounds__(256) void k_lnproj(
    const float* __restrict__ m, const float* __restrict__ mask,
    const float* __restrict__ g, const float* __restrict__ beta,
    const float* __restrict__ b1, const float* __restrict__ b2,
    const ushort_t* __restrict__ WcatT,
    ushort_t* __restrict__ Abig, ushort_t* __restrict__ BbigT) {
    __shared__ ushort_t mnL[64 * CM];   // [row][k] swizzled
    __shared__ ushort_t wL[64 * CM];    // [ch][k] swizzled
    int t = threadIdx.x;
    int sg = blockIdx.x & 7, rg = blockIdx.x >> 3;
    int s0 = sg * 16, r0 = rg * 4;

    // ---- phase 1: LN, 4 lanes per row, 64 floats each ----
    int ml = t >> 2, part = t & 3;
    int r_l = ml >> 4, s_l = ml & 15;
    size_t p = (size_t)(s0 + s_l) * R + (r0 + r_l);
    const float4* row = (const float4*)(m + p * CM + part * 64);
    float4 x[16];
    float sum = 0.f, sq = 0.f;
    #pragma unroll
    for (int i = 0; i < 16; ++i) {
        x[i] = row[i];
        sum += x[i].x + x[i].y + x[i].z + x[i].w;
        sq  += x[i].x * x[i].x + x[i].y * x[i].y
             + x[i].z * x[i].z + x[i].w * x[i].w;
    }
    sum += __shfl_xor(sum, 1); sum += __shfl_xor(sum, 2);
    sq  += __shfl_xor(sq, 1);  sq  += __shfl_xor(sq, 2);
    float mean = sum * (1.0f / CM);
    float var  = sq * (1.0f / CM) - mean * mean;
    float inv  = rsqrtf(var + 1e-5f);
    const float4* g4 = (const float4*)(g + part * 64);
    const float4* be4 = (const float4*)(beta + part * 64);
    #pragma unroll
    for (int c8 = 0; c8 < 8; ++c8) {
        float4 a = x[2 * c8], b = x[2 * c8 + 1];
        float4 ga = g4[2 * c8], gb = g4[2 * c8 + 1];
        float4 ba = be4[2 * c8], bb = be4[2 * c8 + 1];
        union { ushort_t u[8]; uint4 v; } pk;
        pk.u[0] = f2bf((a.x - mean) * inv * ga.x + ba.x);
        pk.u[1] = f2bf((a.y - mean) * inv * ga.y + ba.y);
        pk.u[2] = f2bf((a.z - mean) * inv * ga.z + ba.z);
        pk.u[3] = f2bf((a.w - mean) * inv * ga.w + ba.w);
        pk.u[4] = f2bf((b.x - mean) * inv * gb.x + bb.x);
        pk.u[5] = f2bf((b.y - mean) * inv * gb.y + bb.y);
        pk.u[6] = f2bf((b.z - mean) * inv * gb.z + bb.z);
        pk.u[7] = f2bf((b.w - mean) * inv * gb.w + bb.w);
        int ck = part * 8 + c8;
        int phys = ck ^ (ml & 15);
        *(uint4*)&mnL[ml * CM + phys * 8] = pk.v;
    }
    // ---- phase 2: stage WcatT (coalesced) ----
    #pragma unroll
    for (int it = 0; it < 8; ++it) {
        int v = t + it * 256;
        int ch = v >> 5, ck = v & 31;
        int phys = ck ^ (ch & 15);
        *(uint4*)&wL[ch * CM + phys * 8] =
            *(const uint4*)&WcatT[(size_t)ch * CM + ck * 8];
    }
    __syncthreads();

    // ---- phase 3: MFMA  D[m=64][n=16 per wave], K=256 ----
    int w = t >> 6, lane = t & 63, quad = lane >> 4, l15 = lane & 15;
    int ch = w * 16 + l15;
    f32x4 acc[4];
    #pragma unroll
    for (int a = 0; a < 4; a++) acc[a] = (f32x4)(0.f);
    #pragma unroll
    for (int ks = 0; ks < 8; ++ks) {
        int cb = ks * 4 + quad;
        short8 bfr = *(const short8*)&wL[ch * CM + ((cb ^ l15) << 3)];
        #pragma unroll
        for (int mt = 0; mt < 4; ++mt) {
            int mm = mt * 16 + l15;
            short8 afr = *(const short8*)&mnL[mm * CM + ((cb ^ l15) << 3)];
            acc[mt] = __builtin_amdgcn_mfma_f32_16x16x32_bf16(afr, bfr, acc[mt], 0, 0, 0);
        }
    }

    // ---- epilogue: bias + mask, 8B stores ----
    int c = ch & 31;
    float bias = (ch < CH) ? b1[c] : b2[c];
    ushort_t* dst = (ch < CH) ? Abig : BbigT;
    #pragma unroll
    for (int mt = 0; mt < 4; ++mt) {
        int r = r0 + mt;
        union { ushort_t u[4]; uint2 v; } pk;
        #pragma unroll
        for (int reg = 0; reg < 4; ++reg) {
            int s = s0 + quad * 4 + reg;
            float mv = mask[(size_t)s * R + r];
            pk.u[reg] = f2bf((acc[mt][reg] + bias) * mv);
        }
        *(uint2*)&dst[((size_t)r * CH + c) * S + s0 + quad * 4] = pk.v;
    }
}

// ---------------------------------------------------------------------------
// K2: bf16 MFMA GEMM  D[m][n] = sum_k Abig[m][k] * BbigT[n][k]
// ---------------------------------------------------------------------------
__global__ __launch_bounds__(256) void k_outer(
    const ushort_t* __restrict__ Abig, const ushort_t* __restrict__ BbigT,
    ushort_t* __restrict__ OC, int ib) {
    __shared__ ushort_t shA[128 * 128];
    __shared__ ushort_t shB[128 * 128];
    int t = threadIdx.x;
    int mb = ib * CH + blockIdx.y * 128;
    int nb = blockIdx.x * 128;

    #pragma unroll
    for (int it = 0; it < 8; ++it) {
        int v = t + it * 256;
        int row = v >> 4, chk = v & 15;
        int sw = (chk ^ (row & 7)) << 3;
        *(float4*)&shA[row * 128 + sw] =
            *(const float4*)&Abig[(size_t)(mb + row) * S + (chk << 3)];
        *(float4*)&shB[row * 128 + sw] =
            *(const float4*)&BbigT[(size_t)(nb + row) * S + (chk << 3)];
    }
    __syncthreads();

    int w = t >> 6, lane = t & 63;
    int quad = lane >> 4, l15 = lane & 15;
    int wm = (w & 1) * 64, wn = (w >> 1) * 64;

    f32x4 acc[4][4];
    #pragma unroll
    for (int a = 0; a < 4; a++)
        #pragma unroll
        for (int b = 0; b < 4; b++) acc[a][b] = (f32x4)(0.f);

    #pragma unroll
    for (int ks = 0; ks < 4; ++ks) {
        int qk = ks * 4 + quad;
        short8 af[4], bfr[4];
        #pragma unroll
        for (int mt = 0; mt < 4; ++mt) {
            int mm = wm + mt * 16 + l15;
            af[mt] = *(const short8*)&shA[mm * 128 + ((qk ^ (mm & 7)) << 3)];
        }
        #pragma unroll
        for (int nt = 0; nt < 4; ++nt) {
            int nn = wn + nt * 16 + l15;
            bfr[nt] = *(const short8*)&shB[nn * 128 + ((qk ^ (nn & 7)) << 3)];
        }
        #pragma unroll
        for (int mt = 0; mt < 4; ++mt)
            #pragma unroll
            for (int nt = 0; nt < 4; ++nt)
                acc[mt][nt] = __builtin_amdgcn_mfma_f32_16x16x32_bf16(
                    af[mt], bfr[nt], acc[mt][nt], 0, 0, 0);
    }

    #pragma unroll
    for (int mt = 0; mt < 4; ++mt) {
        #pragma unroll
        for (int reg = 0; reg < 4; ++reg) {
            int lm = blockIdx.y * 128 + wm + mt * 16 + quad * 4 + reg;
            int il = lm >> 5, c = lm & 31;
            #pragma unroll
            for (int nt = 0; nt < 4; ++nt) {
                int gn = nb + wn + nt * 16 + l15;
                int j = gn >> 5, e = gn & 31;
                OC[(((size_t)il * R + j) << 10) + c * 32 + e] =
                    f2bf(acc[mt][nt][reg]);
            }
        }
    }
}

// ---------------------------------------------------------------------------
// K3: out[p][z] = (sum_k OC[p][k] * WT[z][k] + b_out[z]) * scale[p]
//     M = CI*256, N = 128, K = 1024.  256 rows/block (4 waves x 64 rows):
//     WT re-read halved vs 128-row blocks. No LDS.
// ---------------------------------------------------------------------------
__global__ __launch_bounds__(256) void k_proj(
    const ushort_t* __restrict__ OC, const ushort_t* __restrict__ WT,
    const float* __restrict__ b_out, const float* __restrict__ scale,
    float* __restrict__ out, int ib) {
    int t = threadIdx.x;
    int w = t >> 6, lane = t & 63;
    int quad = lane >> 4, l15 = lane & 15;
    int rb = blockIdx.x * 256 + w * 64;     // chunk-local pair row base

    f32x4 acc[4][8];
    #pragma unroll
    for (int a = 0; a < 4; a++)
        #pragma unroll
        for (int b = 0; b < 8; b++) acc[a][b] = (f32x4)(0.f);

    #pragma unroll 2
    for (int kk = 0; kk < 32; ++kk) {
        int ko = kk * 32 + quad * 8;
        short8 af[4], bfr[8];
        #pragma unroll
        for (int mt = 0; mt < 4; ++mt)
            af[mt] = *(const short8*)&OC[(size_t)(rb + mt * 16 + l15) * 1024 + ko];
        #pragma unroll
        for (int nt = 0; nt < 8; ++nt)
            bfr[nt] = *(const short8*)&WT[(size_t)(nt * 16 + l15) * 1024 + ko];
        #pragma unroll
        for (int mt = 0; mt < 4; ++mt)
            #pragma unroll
            for (int nt = 0; nt < 8; ++nt)
                acc[mt][nt] = __builtin_amdgcn_mfma_f32_16x16x32_bf16(
                    af[mt], bfr[nt], acc[mt][nt], 0, 0, 0);
    }

    float bz[8];
    #pragma unroll
    for (int nt = 0; nt < 8; ++nt) bz[nt] = b_out[nt * 16 + l15];

    #pragma unroll
    for (int mt = 0; mt < 4; ++mt) {
        #pragma unroll
        for (int reg = 0; reg < 4; ++reg) {
            int p = rb + mt * 16 + quad * 4 + reg;
            int pg = ib * R + p;
            float sc = scale[pg];
            #pragma unroll
            for (int nt = 0; nt < 8; ++nt) {
                int z = nt * 16 + l15;
                out[(size_t)pg * CZ + z] = (acc[mt][nt][reg] + bz[nt]) * sc;
            }
        }
    }
}

// ---------------------------------------------------------------------------
extern "C" void kernel_launch(void* const* d_in, const int* in_sizes, int n_in,
                              void* d_out, int out_size, void* d_ws, size_t ws_size,
                              hipStream_t stream) {
    const float* m    = (const float*)d_in[0];
    const float* mask = (const float*)d_in[1];
    const float* g    = (const float*)d_in[2];
    const float* be   = (const float*)d_in[3];
    const float* w1   = (const float*)d_in[4];
    const float* b1   = (const float*)d_in[5];
    const float* w2   = (const float*)d_in[6];
    const float* b2   = (const float*)d_in[7];
    const float* wo   = (const float*)d_in[8];
    const float* bo   = (const float*)d_in[9];
    float* out = (float*)d_out;

    char* ws = (char*)d_ws;
    ushort_t* Abig  = (ushort_t*)ws;                        // 2 MB
    ushort_t* BbigT = Abig + (size_t)R * CH * S;            // 2 MB
    ushort_t* WT    = BbigT + (size_t)R * CH * S;           // 256 KB
    ushort_t* WcatT = WT + (size_t)CZ * CH * CH;            // 32 KB
    float*    scale = (float*)(WcatT + (size_t)64 * CM);    // 256 KB
    ushort_t* OC    = (ushort_t*)(scale + (size_t)R * R);   // CI*512 KB

    size_t fixed = (size_t)R * CH * S * 2 * 2 + (size_t)CZ * CH * CH * 2
                 + (size_t)64 * CM * 2 + (size_t)R * R * 4;
    int CI = 256;
    while (CI > 4 && fixed + (size_t)CI * R * CH * CH * 2 > ws_size)
        CI >>= 1;

    k_norm<<<R, R, 0, stream>>>(mask, scale);
    k_wt<<<CZ, 256, 0, stream>>>(wo, WT);
    k_wprep<<<64, 256, 0, stream>>>(w1, w2, WcatT);
    k_lnproj<<<512, 256, 0, stream>>>(m, mask, g, be, b1, b2, WcatT, Abig, BbigT);
    for (int ib = 0; ib < R; ib += CI) {
        dim3 go(64, CI / 4);
        k_outer<<<go, 256, 0, stream>>>(Abig, BbigT, OC, ib);
        k_proj<<<CI, 256, 0, stream>>>(OC, WT, bo, scale, out, ib);
    }
}